// Round 9
// baseline (299.712 us; speedup 1.0000x reference)
//
#include <hip/hip_runtime.h>

#define D 128
#define CE 8192          // edges per sort chunk
#define NB_MAX 1024      // max buckets of 128 nodes -> nNodes <= 131072
#define MAXC 512         // max chunks
#define EBUF 3072        // bucket gather LDS edge window capacity
#define CHUNK 1024       // tier-2 scan chunk
#define WTP 136          // Wt row pitch in ushorts (also LDS agg pitch)

// out = relu( (sum_e a_e * x[src_e]) @ W + y + bias )   [linearity of GEMM]
// Round 16: fusion retry with LDS UNION. R7 failed only on occupancy
// (64KB LDS -> 2 blk/CU). Gather structures (30.2KB) are dead after the
// last window; agg tile (34KB) lives after. Overlay both in one 34.8KB
// buffer -> 4 blk/CU. Gather body = round-3 proven; MFMA/epilogue = R7
// proven. Deletes agg 51MB write + 51MB read + gemm launch.
// Chain: sort_convert -> bucket_fused.

typedef __attribute__((ext_vector_type(8))) short bf16x8;
typedef __attribute__((ext_vector_type(4))) float f32x4;

__device__ __forceinline__ unsigned short f2bf(float f) {
  unsigned u = __float_as_uint(f);
  unsigned r = (u + 0x7fffu + ((u >> 16) & 1u)) >> 16;  // RNE
  return (unsigned short)r;
}

__device__ __forceinline__ int wave_iscan(int v) {
  const int lane = threadIdx.x & 63;
#pragma unroll
  for (int off = 1; off < 64; off <<= 1) {
    int u = __shfl_up(v, off, 64);
    if (lane >= off) v += u;
  }
  return v;
}

__device__ __forceinline__ int seg_find(const int* pref, int nC, int i) {
  int lo = 0, hi = nC;
  while (hi - lo > 1) {
    int mid = (lo + hi) >> 1;
    if (pref[mid] <= i) lo = mid; else hi = mid;
  }
  return lo;
}

// ===== K1: fused chunk-sort + x->bf16 convert + W transpose (one launch) ===
__global__ __launch_bounds__(1024) void sort_convert_kernel(
    const int* __restrict__ src, const int* __restrict__ dst,
    const float* __restrict__ adj, int2* __restrict__ edges,
    unsigned short* __restrict__ ofs, int nE, int nB, int nC,
    const float4* __restrict__ x4, ushort4* __restrict__ xb4, int n4,
    int nxblk, const float* __restrict__ w, unsigned short* __restrict__ wt) {
  __shared__ int2 stage[CE];       // 64 KB
  __shared__ int h[NB_MAX + 4];    // hist -> exclusive starts
  __shared__ int wsum[16];
  const int bid = blockIdx.x;
  const int t = threadIdx.x;

  if (bid >= nC) {                 // ---- convert path (no LDS use) ----
    int b2 = bid - nC;
    if (b2 < nxblk) {
      int i = b2 * 1024 + t;
      if (i < n4) {
        float4 v = x4[i];
        ushort4 r;
        r.x = f2bf(v.x);
        r.y = f2bf(v.y);
        r.z = f2bf(v.z);
        r.w = f2bf(v.w);
        xb4[i] = r;
      }
    } else {
      int idx = (b2 - nxblk) * 1024 + t;   // 16384 total
      if (idx < D * D) {
        int n = idx >> 7, k = idx & 127;
        wt[n * WTP + k] = f2bf(w[k * D + n]);
      }
    }
    return;
  }

  // ---- sort path ----
  const int c = bid;
  const int e0 = c * CE;
  const int n = min(CE, nE - e0);
  const int lane = t & 63, wid = t >> 6;

  for (int i = t; i < NB_MAX + 4; i += 1024) h[i] = 0;
  __syncthreads();

  // hist pass; atomicAdd return = within-bucket rank (packed into dreg)
  int dreg[8];
#pragma unroll
  for (int k = 0; k < 8; ++k) {
    int i = k * 1024 + t;
    if (i < n) {
      int d = dst[e0 + i];
      int rank = atomicAdd(&h[d >> 7], 1);
      dreg[k] = d | (rank << 17);    // d < 2^17, rank < 2^13
    }
  }
  __syncthreads();

  // shfl-based exclusive scan over 1024 bucket counts (one per thread)
  int v = h[t];
  int inc = wave_iscan(v);
  if (lane == 63) wsum[wid] = inc;
  __syncthreads();
  if (wid == 0) {
    int p = (lane < 16) ? wsum[lane] : 0;
    int pi = wave_iscan(p);
    if (lane < 16) wsum[lane] = pi;
  }
  __syncthreads();
  h[t] = inc - v + (wid ? wsum[wid - 1] : 0);  // exclusive prefix
  __syncthreads();

  // publish bucket starts (h is read-only from here)
  unsigned short* o = ofs + (size_t)c * (nB + 1);
  for (int i = t; i <= nB; i += 1024)
    o[i] = (unsigned short)(i < NB_MAX ? h[i] : n);

  // scatter into LDS stage at start+rank (no atomics)
#pragma unroll
  for (int k = 0; k < 8; ++k) {
    int i = k * 1024 + t;
    if (i < n) {
      int dr = dreg[k];
      int d = dr & 0x1FFFF;
      int rank = ((unsigned)dr) >> 17;
      int pos = h[d >> 7] + rank;
      int2 ev;
      ev.x = src[e0 + i] | ((d & 127) << 17);
      ev.y = __float_as_int(adj[e0 + i]);
      stage[pos] = ev;
    }
  }
  __syncthreads();

  // coalesced write-out
  for (int i = t; i < n; i += 1024) edges[e0 + i] = stage[i];
}

// ====== Fused bucket CSR + gather + MFMA GEMM, LDS-union (34.8KB) =========
// Phase A: round-3 gather (structures in smem[0..30232)).
// Phase B: pack bf16 agg rows into smem (overlay, pitch WTP=136).
// Phase C: 16x16x32 MFMA, A from LDS agg, B from global wt (L2-hot).
// Phase D: +y +bias, relu, store out.
__global__ __launch_bounds__(256) void bucket_fused_kernel(
    const int2* __restrict__ tmp, const unsigned short* __restrict__ ofs,
    const uint2* __restrict__ xb, const unsigned short* __restrict__ wt,
    const float* __restrict__ y, const float* __restrict__ bias,
    float* __restrict__ out, int nC, int nB, int nNodes) {
  __shared__ __align__(16) char smem[34816];   // union: gather structs | agg
  int2* ebuf  = (int2*)smem;                    //  0     .. 24576
  int* segst  = (int*)(smem + 24576);           // 24576 .. 26624
  int* pref   = (int*)(smem + 26624);           // 26624 .. 28680 (513 ints)
  int* cnt    = (int*)(smem + 28680);           // 28680 .. 29192
  int* cur    = (int*)(smem + 29192);           // 29192 .. 29704
  int* sstart = (int*)(smem + 29704);           // 29704 .. 30216
  int* w4     = (int*)(smem + 30216);           // 30216 .. 30232
  unsigned short* agg = (unsigned short*)smem;  // overlay: 128*136*2 = 34816

  const int t = threadIdx.x;
  const int b = blockIdx.x;
  const int lane = t & 63, wid = t >> 6;

  // segment table for this bucket (2 chunks per thread; nC <= 512)
  const int c0 = 2 * t, c1 = 2 * t + 1;
  int n0 = 0, n1 = 0;
  if (c0 < nC) {
    int s0 = ofs[(size_t)c0 * (nB + 1) + b];
    int s1 = ofs[(size_t)c0 * (nB + 1) + b + 1];
    segst[c0] = c0 * CE + s0;
    n0 = s1 - s0;
  }
  if (c1 < nC) {
    int s0 = ofs[(size_t)c1 * (nB + 1) + b];
    int s1 = ofs[(size_t)c1 * (nB + 1) + b + 1];
    segst[c1] = c1 * CE + s0;
    n1 = s1 - s0;
  }
  int tt = n0 + n1;
  int inc = wave_iscan(tt);
  if (lane == 63) w4[wid] = inc;
  __syncthreads();
  int add = 0;
  for (int i = 0; i < wid; ++i) add += w4[i];
  int incl = inc + add;
  int excl = incl - tt;
  if (c0 < nC) pref[c0] = excl;
  if (c1 < nC) pref[c1] = excl + n0;
  if (t == 255) pref[nC] = incl;
  __syncthreads();
  const int m = pref[nC];  // edges in this bucket

  const int gi = t >> 5;   // lane-group 0..7, handles nodes gi*16..gi*16+15
  const int q = t & 31;
  float4 acc[16];
#pragma unroll
  for (int k = 0; k < 16; ++k) acc[k] = make_float4(0.f, 0.f, 0.f, 0.f);

  // ---------------- Phase A: windowed CSR-build + gather ------------------
  for (int w0 = 0; w0 < m; w0 += EBUF) {
    const int w1 = min(m, w0 + EBUF);
    if (t < 128) cnt[t] = 0;
    __syncthreads();

    // count pass (read only src word: 4B)
    for (int i = w0 + t; i < w1; i += 256) {
      int lo = seg_find(pref, nC, i);
      int sx = ((const int*)tmp)[(size_t)(segst[lo] + (i - pref[lo])) * 2];
      atomicAdd(&cnt[(sx >> 17) & 127], 1);
    }
    __syncthreads();

    // scan 128 node counts (2 waves)
    int cv = (t < 128) ? cnt[t] : 0;
    int cinc = wave_iscan(cv);
    if (t == 63) w4[0] = cinc;
    __syncthreads();
    int cst = cinc - cv + ((t >= 64 && t < 128) ? w4[0] : 0);
    if (t < 128) {
      sstart[t] = cst;
      cur[t] = cst;
    }
    __syncthreads();

    // scatter pass: node-grouped records into ebuf
    for (int i = w0 + t; i < w1; i += 256) {
      int lo = seg_find(pref, nC, i);
      int2 ev = tmp[segst[lo] + (i - pref[lo])];
      int pos = atomicAdd(&cur[(ev.x >> 17) & 127], 1);
      ebuf[pos] = ev;
    }
    __syncthreads();

    // gather-accumulate: group gi, node-local dl = gi*16+k
#pragma unroll
    for (int k = 0; k < 16; ++k) {
      const int dl = gi * 16 + k;
      int j = sstart[dl];
      const int e = cur[dl];
      for (; j + 3 < e; j += 4) {
        int2 e0 = ebuf[j], e1 = ebuf[j + 1], e2 = ebuf[j + 2], e3 = ebuf[j + 3];
        float a0 = __int_as_float(e0.y), a1 = __int_as_float(e1.y);
        float a2 = __int_as_float(e2.y), a3 = __int_as_float(e3.y);
        uint2 v0 = xb[(size_t)(e0.x & 0x1FFFF) * 32 + q];
        uint2 v1 = xb[(size_t)(e1.x & 0x1FFFF) * 32 + q];
        uint2 v2 = xb[(size_t)(e2.x & 0x1FFFF) * 32 + q];
        uint2 v3 = xb[(size_t)(e3.x & 0x1FFFF) * 32 + q];
        acc[k].x = fmaf(a0, __uint_as_float(v0.x << 16), acc[k].x);
        acc[k].y = fmaf(a0, __uint_as_float(v0.x & 0xffff0000u), acc[k].y);
        acc[k].z = fmaf(a0, __uint_as_float(v0.y << 16), acc[k].z);
        acc[k].w = fmaf(a0, __uint_as_float(v0.y & 0xffff0000u), acc[k].w);
        acc[k].x = fmaf(a1, __uint_as_float(v1.x << 16), acc[k].x);
        acc[k].y = fmaf(a1, __uint_as_float(v1.x & 0xffff0000u), acc[k].y);
        acc[k].z = fmaf(a1, __uint_as_float(v1.y << 16), acc[k].z);
        acc[k].w = fmaf(a1, __uint_as_float(v1.y & 0xffff0000u), acc[k].w);
        acc[k].x = fmaf(a2, __uint_as_float(v2.x << 16), acc[k].x);
        acc[k].y = fmaf(a2, __uint_as_float(v2.x & 0xffff0000u), acc[k].y);
        acc[k].z = fmaf(a2, __uint_as_float(v2.y << 16), acc[k].z);
        acc[k].w = fmaf(a2, __uint_as_float(v2.y & 0xffff0000u), acc[k].w);
        acc[k].x = fmaf(a3, __uint_as_float(v3.x << 16), acc[k].x);
        acc[k].y = fmaf(a3, __uint_as_float(v3.x & 0xffff0000u), acc[k].y);
        acc[k].z = fmaf(a3, __uint_as_float(v3.y << 16), acc[k].z);
        acc[k].w = fmaf(a3, __uint_as_float(v3.y & 0xffff0000u), acc[k].w);
      }
      for (; j < e; ++j) {
        int2 e0 = ebuf[j];
        float a0 = __int_as_float(e0.y);
        uint2 v0 = xb[(size_t)(e0.x & 0x1FFFF) * 32 + q];
        acc[k].x = fmaf(a0, __uint_as_float(v0.x << 16), acc[k].x);
        acc[k].y = fmaf(a0, __uint_as_float(v0.x & 0xffff0000u), acc[k].y);
        acc[k].z = fmaf(a0, __uint_as_float(v0.y << 16), acc[k].z);
        acc[k].w = fmaf(a0, __uint_as_float(v0.y & 0xffff0000u), acc[k].w);
      }
    }
    __syncthreads();   // ebuf/cnt reused next window
  }
  __syncthreads();     // gather structures dead; smem becomes agg

  // ---------------- Phase B: pack bf16 agg rows into LDS (overlay) --------
#pragma unroll
  for (int k = 0; k < 16; ++k) {
    const int dl = gi * 16 + k;
    uint2 pk;
    pk.x = (unsigned)f2bf(acc[k].x) | ((unsigned)f2bf(acc[k].y) << 16);
    pk.y = (unsigned)f2bf(acc[k].z) | ((unsigned)f2bf(acc[k].w) << 16);
    *(uint2*)&agg[dl * WTP + q * 4] = pk;
  }
  __syncthreads();

  // ---------------- Phase C: MFMA GEMM (A from LDS, B from wt) ------------
  const int w = t >> 6, l = t & 63;
  const int quad = l >> 4, mm = l & 15;
  const int row0 = b * 128 + w * 32;
  const char* pa0 = (const char*)&agg[(w * 32 + mm) * WTP];
  const char* pa1 = (const char*)&agg[(w * 32 + 16 + mm) * WTP];

  f32x4 acc0[8], acc1[8];
#pragma unroll
  for (int nt = 0; nt < 8; ++nt) {
    acc0[nt] = (f32x4){0.f, 0.f, 0.f, 0.f};
    acc1[nt] = (f32x4){0.f, 0.f, 0.f, 0.f};
  }

#pragma unroll
  for (int ks = 0; ks < 4; ++ks) {
    const int kof = ks * 32 + quad * 8;
    bf16x8 a0 = *(const bf16x8*)(pa0 + kof * 2);
    bf16x8 a1 = *(const bf16x8*)(pa1 + kof * 2);
#pragma unroll
    for (int nt = 0; nt < 8; ++nt) {
      bf16x8 bb = *(const bf16x8*)&wt[(nt * 16 + mm) * WTP + kof];
      acc0[nt] = __builtin_amdgcn_mfma_f32_16x16x32_bf16(a0, bb, acc0[nt], 0, 0, 0);
      acc1[nt] = __builtin_amdgcn_mfma_f32_16x16x32_bf16(a1, bb, acc1[nt], 0, 0, 0);
    }
  }

  // ---------------- Phase D: epilogue -------------------------------------
  float bv[8];
#pragma unroll
  for (int nt = 0; nt < 8; ++nt) bv[nt] = bias[nt * 16 + mm];

#pragma unroll
  for (int s = 0; s < 2; ++s) {
#pragma unroll
    for (int r = 0; r < 4; ++r) {
      int row = row0 + s * 16 + quad * 4 + r;
      if (row >= nNodes) continue;
      const float* yr = y + (size_t)row * D;
      float* orow = out + (size_t)row * D;
#pragma unroll
      for (int nt = 0; nt < 8; ++nt) {
        int c = nt * 16 + mm;
        float v = (s == 0 ? acc0[nt][r] : acc1[nt][r]) + yr[c] + bv[nt];
        orow[c] = fmaxf(v, 0.f);
      }
    }
  }
}

// ======================= tier-2/3 fallbacks (proven) =======================
__global__ __launch_bounds__(256) void zero_counts_kernel(int* __restrict__ c, int n) {
  int i = blockIdx.x * 256 + threadIdx.x;
  if (i < n) c[i] = 0;
}

__global__ __launch_bounds__(256) void hist_kernel(
    const int* __restrict__ dst, int* __restrict__ counts, int nE) {
  int e = blockIdx.x * 256 + threadIdx.x;
  if (e < nE) atomicAdd(&counts[dst[e]], 1);
}

__global__ __launch_bounds__(256) void scan_partial_kernel(
    const int* __restrict__ counts, int* __restrict__ chunk_sum, int n) {
  __shared__ int sdata[256];
  int b = blockIdx.x, t = threadIdx.x;
  int base = b * CHUNK + t * 4;
  int s = 0;
#pragma unroll
  for (int k = 0; k < 4; ++k) {
    int i = base + k;
    if (i < n) s += counts[i];
  }
  sdata[t] = s;
  __syncthreads();
  for (int off = 128; off > 0; off >>= 1) {
    if (t < off) sdata[t] += sdata[t + off];
    __syncthreads();
  }
  if (t == 0) chunk_sum[b] = sdata[0];
}

__global__ void scan_chunks_kernel(const int* __restrict__ chunk_sum,
                                   int* __restrict__ chunk_off,
                                   int* __restrict__ row_start, int nchunks, int n) {
  if (threadIdx.x == 0 && blockIdx.x == 0) {
    int run = 0;
    for (int i = 0; i < nchunks; ++i) {
      chunk_off[i] = run;
      run += chunk_sum[i];
    }
    row_start[n] = run;
  }
}

__global__ __launch_bounds__(256) void scan_final_kernel(
    const int* __restrict__ counts, const int* __restrict__ chunk_off,
    int* __restrict__ row_start, int* __restrict__ cursor, int n) {
  __shared__ int sdata[256];
  int b = blockIdx.x, t = threadIdx.x;
  int base = b * CHUNK + t * 4;
  int c[4] = {0, 0, 0, 0};
#pragma unroll
  for (int k = 0; k < 4; ++k) {
    int i = base + k;
    if (i < n) c[k] = counts[i];
  }
  int tsum = c[0] + c[1] + c[2] + c[3];
  sdata[t] = tsum;
  __syncthreads();
  for (int off = 1; off < 256; off <<= 1) {
    int v = (t >= off) ? sdata[t - off] : 0;
    __syncthreads();
    sdata[t] += v;
    __syncthreads();
  }
  int run = sdata[t] - tsum + chunk_off[b];
#pragma unroll
  for (int k = 0; k < 4; ++k) {
    int i = base + k;
    if (i < n) {
      row_start[i] = run;
      cursor[i] = run;
      run += c[k];
    }
  }
}

__global__ __launch_bounds__(256) void scatter_sort_kernel(
    const int* __restrict__ src, const int* __restrict__ dst,
    const float* __restrict__ adj, int* __restrict__ cursor,
    int2* __restrict__ edges, int nE) {
  int e = blockIdx.x * 256 + threadIdx.x;
  if (e >= nE) return;
  int d = dst[e];
  int2 ev;
  ev.x = src[e];
  ev.y = __float_as_int(adj[e]);
  int pos = atomicAdd(&cursor[d], 1);
  edges[pos] = ev;
}

__global__ __launch_bounds__(256) void gather_fp32_kernel(
    const float* __restrict__ x, const int* __restrict__ row_start,
    const int2* __restrict__ edges, float* __restrict__ out, int nNodes) {
  int g = (blockIdx.x * 256 + threadIdx.x) >> 5;
  int q = threadIdx.x & 31;
  if (g >= nNodes) return;
  int beg = row_start[g], end = row_start[g + 1];
  const float4* x4 = (const float4*)x;
  float4 acc = make_float4(0.f, 0.f, 0.f, 0.f);
  for (int j = beg; j < end; ++j) {
    int2 e0 = edges[j];
    float a0 = __int_as_float(e0.y);
    float4 v0 = x4[(size_t)e0.x * 32 + q];
    acc.x = fmaf(a0, v0.x, acc.x);
    acc.y = fmaf(a0, v0.y, acc.y);
    acc.z = fmaf(a0, v0.z, acc.z);
    acc.w = fmaf(a0, v0.w, acc.w);
  }
  ((float4*)out)[(size_t)g * 32 + q] = acc;
}

__global__ __launch_bounds__(256) void zero_kernel(float4* __restrict__ out, int n4) {
  int i = blockIdx.x * 256 + threadIdx.x;
  if (i < n4) out[i] = make_float4(0.f, 0.f, 0.f, 0.f);
}

__global__ __launch_bounds__(256) void scatter_atomic_kernel(
    const float* __restrict__ x, const int* __restrict__ src,
    const int* __restrict__ dst, const float* __restrict__ adj,
    float* __restrict__ out, int nE) {
  int tid = blockIdx.x * 256 + threadIdx.x;
  int e = tid >> 5;
  int q = tid & 31;
  if (e >= nE) return;
  int s = src[e];
  int d = dst[e];
  float a = adj[e];
  float4 v = ((const float4*)x)[(size_t)s * 32 + q];
  float* o = out + (size_t)d * D + q * 4;
  atomicAdd(o + 0, v.x * a);
  atomicAdd(o + 1, v.y * a);
  atomicAdd(o + 2, v.z * a);
  atomicAdd(o + 3, v.w * a);
}

// tier-2/3 epilogue GEMM (fp32 in-place)
__global__ __launch_bounds__(256) void gemm_fused_kernel(
    float* __restrict__ out, const float* __restrict__ w,
    const float* __restrict__ y, const float* __restrict__ bias, int nrows) {
  __shared__ float sW[D * D];
  __shared__ float sA[32 * D];
  const int tid = threadIdx.x;
  const int row0 = blockIdx.x * 32;

  const float4* w4 = (const float4*)w;
  float4* sW4 = (float4*)sW;
  for (int i = tid; i < D * D / 4; i += 256) sW4[i] = w4[i];

  const int nrow_blk = min(32, nrows - row0);
  const float4* out4_base = (const float4*)(out + (size_t)row0 * D);
  float4* sA4 = (float4*)sA;
  for (int i = tid; i < nrow_blk * 32; i += 256) sA4[i] = out4_base[i];
  __syncthreads();

  const int cg = tid & 31;
  const int rs = tid >> 5;

  float4 acc[4];
#pragma unroll
  for (int r = 0; r < 4; ++r) acc[r] = make_float4(0.f, 0.f, 0.f, 0.f);

#pragma unroll 4
  for (int k4 = 0; k4 < 32; ++k4) {
    float4 wv0 = sW4[(k4 * 4 + 0) * 32 + cg];
    float4 wv1 = sW4[(k4 * 4 + 1) * 32 + cg];
    float4 wv2 = sW4[(k4 * 4 + 2) * 32 + cg];
    float4 wv3 = sW4[(k4 * 4 + 3) * 32 + cg];
#pragma unroll
    for (int r = 0; r < 4; ++r) {
      float4 xv = sA4[(rs + r * 8) * 32 + k4];
      acc[r].x = fmaf(xv.x, wv0.x, acc[r].x);
      acc[r].y = fmaf(xv.x, wv0.y, acc[r].y);
      acc[r].z = fmaf(xv.x, wv0.z, acc[r].z);
      acc[r].w = fmaf(xv.x, wv0.w, acc[r].w);
      acc[r].x = fmaf(xv.y, wv1.x, acc[r].x);
      acc[r].y = fmaf(xv.y, wv1.y, acc[r].y);
      acc[r].z = fmaf(xv.y, wv1.z, acc[r].z);
      acc[r].w = fmaf(xv.y, wv1.w, acc[r].w);
      acc[r].x = fmaf(xv.z, wv2.x, acc[r].x);
      acc[r].y = fmaf(xv.z, wv2.y, acc[r].y);
      acc[r].z = fmaf(xv.z, wv2.z, acc[r].z);
      acc[r].w = fmaf(xv.z, wv2.w, acc[r].w);
      acc[r].x = fmaf(xv.w, wv3.x, acc[r].x);
      acc[r].y = fmaf(xv.w, wv3.y, acc[r].y);
      acc[r].z = fmaf(xv.w, wv3.z, acc[r].z);
      acc[r].w = fmaf(xv.w, wv3.w, acc[r].w);
    }
  }

  const float4* y4 = (const float4*)y;
  const float4* b4 = (const float4*)bias;
  float4* o4 = (float4*)out;
  float4 bv = b4[cg];
#pragma unroll
  for (int r = 0; r < 4; ++r) {
    int row = row0 + rs + r * 8;
    if (row < nrows) {
      float4 yv = y4[(size_t)row * 32 + cg];
      float4 res;
      res.x = fmaxf(acc[r].x + yv.x + bv.x, 0.f);
      res.y = fmaxf(acc[r].y + yv.y + bv.y, 0.f);
      res.z = fmaxf(acc[r].z + yv.z + bv.z, 0.f);
      res.w = fmaxf(acc[r].w + yv.w + bv.w, 0.f);
      o4[(size_t)row * 32 + cg] = res;
    }
  }
}

extern "C" void kernel_launch(void* const* d_in, const int* in_sizes, int n_in,
                              void* d_out, int out_size, void* d_ws, size_t ws_size,
                              hipStream_t stream) {
  const float* x    = (const float*)d_in[0];
  const float* y    = (const float*)d_in[1];
  const int*   esrc = (const int*)d_in[2];
  const int*   edst = (const int*)d_in[3];
  const float* adj  = (const float*)d_in[4];
  const float* w    = (const float*)d_in[5];
  const float* bias = (const float*)d_in[6];
  float* out = (float*)d_out;

  const int nNodes = in_sizes[0] / D;
  const int nE = in_sizes[2];
  const int n4 = nNodes * (D / 4);
  const int nB = (nNodes + 127) >> 7;
  const int nC = (nE + CE - 1) / CE;

  // tier-1 ws: [ofs | wt | tmp | xb]  (tmp and xb coexist)
  const size_t ofs_bytes = (((size_t)nC * (nB + 1) * 2) + 15) & ~(size_t)15;
  const size_t wt_bytes  = (size_t)D * WTP * 2;
  const size_t tmp_bytes = (size_t)nC * CE * 8;
  const size_t xb_bytes  = (size_t)nNodes * D * 2;
  const size_t need1 = ofs_bytes + wt_bytes + tmp_bytes + xb_bytes;

  const int nchunks = (nNodes + CHUNK - 1) / CHUNK;
  const size_t e2_bytes  = (size_t)nE * 8;
  const size_t int_bytes = (size_t)(3 * nNodes + 1 + 2 * nchunks) * 4;
  const size_t need2 = e2_bytes + int_bytes;

  if (ws_size >= need1 && nNodes <= NB_MAX * 128 && nC <= MAXC) {
    char* p = (char*)d_ws;
    unsigned short* ofs = (unsigned short*)p;   p += ofs_bytes;
    unsigned short* wt = (unsigned short*)p;    p += wt_bytes;
    int2* tmp = (int2*)p;                       p += tmp_bytes;
    ushort4* xb4 = (ushort4*)p;

    const int nxblk = (n4 + 1023) / 1024;
    const int wtblk = (D * D + 1023) / 1024;
    sort_convert_kernel<<<nC + nxblk + wtblk, 1024, 0, stream>>>(
        esrc, edst, adj, tmp, ofs, nE, nB, nC,
        (const float4*)x, xb4, n4, nxblk, w, wt);
    bucket_fused_kernel<<<nB, 256, 0, stream>>>(
        tmp, ofs, (const uint2*)xb4, wt, y, bias, out, nC, nB, nNodes);
  } else if (ws_size >= need2) {
    char* base = (char*)d_ws;
    int2* edges = (int2*)base;
    int* counts = (int*)(base + e2_bytes);
    int* row_start = counts + nNodes;
    int* cursor = row_start + nNodes + 1;
    int* chunk_sum = cursor + nNodes;
    int* chunk_off = chunk_sum + nchunks;

    zero_counts_kernel<<<(nNodes + 255) / 256, 256, 0, stream>>>(counts, nNodes);
    hist_kernel<<<(nE + 255) / 256, 256, 0, stream>>>(edst, counts, nE);
    scan_partial_kernel<<<nchunks, 256, 0, stream>>>(counts, chunk_sum, nNodes);
    scan_chunks_kernel<<<1, 64, 0, stream>>>(chunk_sum, chunk_off, row_start,
                                             nchunks, nNodes);
    scan_final_kernel<<<nchunks, 256, 0, stream>>>(counts, chunk_off, row_start,
                                                   cursor, nNodes);
    scatter_sort_kernel<<<(nE + 255) / 256, 256, 0, stream>>>(
        esrc, edst, adj, cursor, edges, nE);
    gather_fp32_kernel<<<(nNodes * 32 + 255) / 256, 256, 0, stream>>>(
        x, row_start, edges, out, nNodes);
    gemm_fused_kernel<<<(nNodes + 31) / 32, 256, 0, stream>>>(out, w, y, bias,
                                                              nNodes);
  } else {
    zero_kernel<<<(n4 + 255) / 256, 256, 0, stream>>>((float4*)out, n4);
    scatter_atomic_kernel<<<((size_t)nE * 32 + 255) / 256, 256, 0, stream>>>(
        x, esrc, edst, adj, out, nE);
    gemm_fused_kernel<<<(nNodes + 31) / 32, 256, 0, stream>>>(out, w, y, bias,
                                                              nNodes);
  }
}

// Round 10
// 257.777 us; speedup vs baseline: 1.1627x; 1.1627x over previous
//
#include <hip/hip_runtime.h>

#define D 128
#define CE 8192          // edges per sort chunk
#define NB_MAX 1024      // max buckets of 128 nodes -> nNodes <= 131072
#define MAXC 512         // max chunks
#define EBUF 3072        // bucket gather LDS edge window capacity
#define CHUNK 1024       // tier-2 scan chunk
#define WTP 136          // Wt row pitch in ushorts (also LDS tile pitch)

// out = relu( spmm(adj, x@W) + y + bias )
// Round 17: REORDERED algebra (support-first, standard GraphConv order).
// R7/R9 proved in-kernel fusion dead (162us both, register-resident cap).
// New chain: sort_convert -> gemm_support (xb@Wt -> bf16 IN-PLACE over xb,
// 51MB traffic vs old 154MB) -> gather_final (R3-proven gather body reading
// support; epilogue relu(acc+y+bias) fused as coalesced float4 stores).
// Gather gains coalesced y/out streams (not BW-saturated); gemm shrinks ~45us.

typedef __attribute__((ext_vector_type(8))) short bf16x8;
typedef __attribute__((ext_vector_type(4))) float f32x4;

__device__ __forceinline__ unsigned short f2bf(float f) {
  unsigned u = __float_as_uint(f);
  unsigned r = (u + 0x7fffu + ((u >> 16) & 1u)) >> 16;  // RNE
  return (unsigned short)r;
}

__device__ __forceinline__ int wave_iscan(int v) {
  const int lane = threadIdx.x & 63;
#pragma unroll
  for (int off = 1; off < 64; off <<= 1) {
    int u = __shfl_up(v, off, 64);
    if (lane >= off) v += u;
  }
  return v;
}

__device__ __forceinline__ int seg_find(const int* pref, int nC, int i) {
  int lo = 0, hi = nC;
  while (hi - lo > 1) {
    int mid = (lo + hi) >> 1;
    if (pref[mid] <= i) lo = mid; else hi = mid;
  }
  return lo;
}

// ===== K1: fused chunk-sort + x->bf16 convert + W transpose (R8 proven) ====
__global__ __launch_bounds__(1024) void sort_convert_kernel(
    const int* __restrict__ src, const int* __restrict__ dst,
    const float* __restrict__ adj, int2* __restrict__ edges,
    unsigned short* __restrict__ ofs, int nE, int nB, int nC,
    const float4* __restrict__ x4, ushort4* __restrict__ xb4, int n4,
    int nxblk, const float* __restrict__ w, unsigned short* __restrict__ wt) {
  __shared__ int2 stage[CE];       // 64 KB
  __shared__ int h[NB_MAX + 4];    // hist -> exclusive starts
  __shared__ int wsum[16];
  const int bid = blockIdx.x;
  const int t = threadIdx.x;

  if (bid >= nC) {                 // ---- convert path (no LDS use) ----
    int b2 = bid - nC;
    if (b2 < nxblk) {
      int i = b2 * 1024 + t;
      if (i < n4) {
        float4 v = x4[i];
        ushort4 r;
        r.x = f2bf(v.x);
        r.y = f2bf(v.y);
        r.z = f2bf(v.z);
        r.w = f2bf(v.w);
        xb4[i] = r;
      }
    } else {
      int idx = (b2 - nxblk) * 1024 + t;   // 16384 total
      if (idx < D * D) {
        int n = idx >> 7, k = idx & 127;
        wt[n * WTP + k] = f2bf(w[k * D + n]);
      }
    }
    return;
  }

  // ---- sort path ----
  const int c = bid;
  const int e0 = c * CE;
  const int n = min(CE, nE - e0);
  const int lane = t & 63, wid = t >> 6;

  for (int i = t; i < NB_MAX + 4; i += 1024) h[i] = 0;
  __syncthreads();

  // hist pass; atomicAdd return = within-bucket rank (packed into dreg)
  int dreg[8];
#pragma unroll
  for (int k = 0; k < 8; ++k) {
    int i = k * 1024 + t;
    if (i < n) {
      int d = dst[e0 + i];
      int rank = atomicAdd(&h[d >> 7], 1);
      dreg[k] = d | (rank << 17);    // d < 2^17, rank < 2^13
    }
  }
  __syncthreads();

  // shfl-based exclusive scan over 1024 bucket counts (one per thread)
  int v = h[t];
  int inc = wave_iscan(v);
  if (lane == 63) wsum[wid] = inc;
  __syncthreads();
  if (wid == 0) {
    int p = (lane < 16) ? wsum[lane] : 0;
    int pi = wave_iscan(p);
    if (lane < 16) wsum[lane] = pi;
  }
  __syncthreads();
  h[t] = inc - v + (wid ? wsum[wid - 1] : 0);  // exclusive prefix
  __syncthreads();

  // publish bucket starts (h is read-only from here)
  unsigned short* o = ofs + (size_t)c * (nB + 1);
  for (int i = t; i <= nB; i += 1024)
    o[i] = (unsigned short)(i < NB_MAX ? h[i] : n);

  // scatter into LDS stage at start+rank (no atomics)
#pragma unroll
  for (int k = 0; k < 8; ++k) {
    int i = k * 1024 + t;
    if (i < n) {
      int dr = dreg[k];
      int d = dr & 0x1FFFF;
      int rank = ((unsigned)dr) >> 17;
      int pos = h[d >> 7] + rank;
      int2 ev;
      ev.x = src[e0 + i] | ((d & 127) << 17);
      ev.y = __float_as_int(adj[e0 + i]);
      stage[pos] = ev;
    }
  }
  __syncthreads();

  // coalesced write-out
  for (int i = t; i < n; i += 1024) edges[e0 + i] = stage[i];
}

// ===== K2: support = xb @ Wt, bf16, IN-PLACE over xb =======================
// Block i owns rows [128i, 128i+128). All A-fragments preloaded before any
// write (in-place safe; clamped tail rows stay within the last block).
// Output staged through LDS (sWt region reused) for coalesced 16B stores.
__global__ __launch_bounds__(256) void gemm_support_kernel(
    unsigned short* __restrict__ xb, const unsigned short* __restrict__ wt,
    int nNodes) {
  __shared__ unsigned short sWt[D * WTP];  // 34 KB: Wt, then out-tile
  const int t = threadIdx.x;
  for (int i = t; i < D * WTP / 8; i += 256)
    ((int4*)sWt)[i] = ((const int4*)wt)[i];
  __syncthreads();

  const int w = t >> 6, l = t & 63;
  const int quad = l >> 4, m = l & 15;
  const int row0 = blockIdx.x * 128 + w * 32;
  const int ar0 = min(row0 + m, nNodes - 1);
  const int ar1 = min(row0 + 16 + m, nNodes - 1);
  const unsigned short* pa0 = xb + (size_t)ar0 * D;
  const unsigned short* pa1 = xb + (size_t)ar1 * D;

  // preload ALL A fragments (before any write to xb)
  bf16x8 a0[4], a1[4];
#pragma unroll
  for (int ks = 0; ks < 4; ++ks) {
    const int kof = ks * 32 + quad * 8;
    a0[ks] = *(const bf16x8*)(pa0 + kof);
    a1[ks] = *(const bf16x8*)(pa1 + kof);
  }

  f32x4 acc0[8], acc1[8];
#pragma unroll
  for (int nt = 0; nt < 8; ++nt) {
    acc0[nt] = (f32x4){0.f, 0.f, 0.f, 0.f};
    acc1[nt] = (f32x4){0.f, 0.f, 0.f, 0.f};
  }

#pragma unroll
  for (int ks = 0; ks < 4; ++ks) {
    const int kof = ks * 32 + quad * 8;
#pragma unroll
    for (int nt = 0; nt < 8; ++nt) {
      bf16x8 b = *(const bf16x8*)&sWt[(nt * 16 + m) * WTP + kof];
      acc0[nt] = __builtin_amdgcn_mfma_f32_16x16x32_bf16(a0[ks], b, acc0[nt], 0, 0, 0);
      acc1[nt] = __builtin_amdgcn_mfma_f32_16x16x32_bf16(a1[ks], b, acc1[nt], 0, 0, 0);
    }
  }
  __syncthreads();   // all sWt reads done -> reuse as out tile

  // scatter bf16 results into LDS tile [128][WTP]
#pragma unroll
  for (int s = 0; s < 2; ++s) {
#pragma unroll
    for (int r = 0; r < 4; ++r) {
      int rl = w * 32 + s * 16 + quad * 4 + r;
#pragma unroll
      for (int nt = 0; nt < 8; ++nt)
        sWt[rl * WTP + nt * 16 + m] =
            f2bf(s == 0 ? acc0[nt][r] : acc1[nt][r]);
    }
  }
  __syncthreads();

  // coalesced copy tile -> xb rows (pitch 136 -> 128)
  const int base = blockIdx.x * 128;
  for (int c = t; c < 128 * 16; c += 256) {   // 16B chunks
    int rl = c >> 4, co = c & 15;
    int g = base + rl;
    if (g < nNodes)
      *(int4*)&xb[(size_t)g * D + co * 8] = *(const int4*)&sWt[rl * WTP + co * 8];
  }
}

// ===== K3: bucket-CSR + gather of support rows + final epilogue ===========
// R3-proven gather body; sb = support table (bf16, 256B rows).
// Epilogue: out_row = relu(acc + y_row + bias), coalesced float4.
__global__ __launch_bounds__(256) void gather_final_kernel(
    const int2* __restrict__ tmp, const unsigned short* __restrict__ ofs,
    const uint2* __restrict__ sb, const float* __restrict__ y,
    const float* __restrict__ bias, float* __restrict__ out,
    int nC, int nB, int nNodes) {
  __shared__ int2 ebuf[EBUF];      // 24 KB node-grouped window edges
  __shared__ int segst[MAXC];
  __shared__ int pref[MAXC + 1];
  __shared__ int cnt[128];
  __shared__ int cur[128];
  __shared__ int sstart[128];
  __shared__ int w4[4];
  const int t = threadIdx.x;
  const int b = blockIdx.x;
  const int lane = t & 63, wid = t >> 6;

  // segment table for this bucket (2 chunks per thread; nC <= 512)
  const int c0 = 2 * t, c1 = 2 * t + 1;
  int n0 = 0, n1 = 0;
  if (c0 < nC) {
    int s0 = ofs[(size_t)c0 * (nB + 1) + b];
    int s1 = ofs[(size_t)c0 * (nB + 1) + b + 1];
    segst[c0] = c0 * CE + s0;
    n0 = s1 - s0;
  }
  if (c1 < nC) {
    int s0 = ofs[(size_t)c1 * (nB + 1) + b];
    int s1 = ofs[(size_t)c1 * (nB + 1) + b + 1];
    segst[c1] = c1 * CE + s0;
    n1 = s1 - s0;
  }
  int tt = n0 + n1;
  int inc = wave_iscan(tt);
  if (lane == 63) w4[wid] = inc;
  __syncthreads();
  int add = 0;
  for (int i = 0; i < wid; ++i) add += w4[i];
  int incl = inc + add;
  int excl = incl - tt;
  if (c0 < nC) pref[c0] = excl;
  if (c1 < nC) pref[c1] = excl + n0;
  if (t == 255) pref[nC] = incl;
  __syncthreads();
  const int m = pref[nC];  // edges in this bucket

  const int gi = t >> 5;   // lane-group 0..7, handles nodes gi*16..gi*16+15
  const int q = t & 31;
  float4 acc[16];
#pragma unroll
  for (int k = 0; k < 16; ++k) acc[k] = make_float4(0.f, 0.f, 0.f, 0.f);

  for (int w0 = 0; w0 < m; w0 += EBUF) {
    const int w1 = min(m, w0 + EBUF);
    if (t < 128) cnt[t] = 0;
    __syncthreads();

    // count pass (read only src word: 4B)
    for (int i = w0 + t; i < w1; i += 256) {
      int lo = seg_find(pref, nC, i);
      int sx = ((const int*)tmp)[(size_t)(segst[lo] + (i - pref[lo])) * 2];
      atomicAdd(&cnt[(sx >> 17) & 127], 1);
    }
    __syncthreads();

    // scan 128 node counts (2 waves)
    int cv = (t < 128) ? cnt[t] : 0;
    int cinc = wave_iscan(cv);
    if (t == 63) w4[0] = cinc;
    __syncthreads();
    int cst = cinc - cv + ((t >= 64 && t < 128) ? w4[0] : 0);
    if (t < 128) {
      sstart[t] = cst;
      cur[t] = cst;
    }
    __syncthreads();

    // scatter pass: node-grouped records into ebuf
    for (int i = w0 + t; i < w1; i += 256) {
      int lo = seg_find(pref, nC, i);
      int2 ev = tmp[segst[lo] + (i - pref[lo])];
      int pos = atomicAdd(&cur[(ev.x >> 17) & 127], 1);
      ebuf[pos] = ev;
    }
    __syncthreads();

    // gather-accumulate: group gi, node-local dl = gi*16+k
#pragma unroll
    for (int k = 0; k < 16; ++k) {
      const int dl = gi * 16 + k;
      int j = sstart[dl];
      const int e = cur[dl];
      for (; j + 3 < e; j += 4) {
        int2 e0 = ebuf[j], e1 = ebuf[j + 1], e2 = ebuf[j + 2], e3 = ebuf[j + 3];
        float a0 = __int_as_float(e0.y), a1 = __int_as_float(e1.y);
        float a2 = __int_as_float(e2.y), a3 = __int_as_float(e3.y);
        uint2 v0 = sb[(size_t)(e0.x & 0x1FFFF) * 32 + q];
        uint2 v1 = sb[(size_t)(e1.x & 0x1FFFF) * 32 + q];
        uint2 v2 = sb[(size_t)(e2.x & 0x1FFFF) * 32 + q];
        uint2 v3 = sb[(size_t)(e3.x & 0x1FFFF) * 32 + q];
        acc[k].x = fmaf(a0, __uint_as_float(v0.x << 16), acc[k].x);
        acc[k].y = fmaf(a0, __uint_as_float(v0.x & 0xffff0000u), acc[k].y);
        acc[k].z = fmaf(a0, __uint_as_float(v0.y << 16), acc[k].z);
        acc[k].w = fmaf(a0, __uint_as_float(v0.y & 0xffff0000u), acc[k].w);
        acc[k].x = fmaf(a1, __uint_as_float(v1.x << 16), acc[k].x);
        acc[k].y = fmaf(a1, __uint_as_float(v1.x & 0xffff0000u), acc[k].y);
        acc[k].z = fmaf(a1, __uint_as_float(v1.y << 16), acc[k].z);
        acc[k].w = fmaf(a1, __uint_as_float(v1.y & 0xffff0000u), acc[k].w);
        acc[k].x = fmaf(a2, __uint_as_float(v2.x << 16), acc[k].x);
        acc[k].y = fmaf(a2, __uint_as_float(v2.x & 0xffff0000u), acc[k].y);
        acc[k].z = fmaf(a2, __uint_as_float(v2.y << 16), acc[k].z);
        acc[k].w = fmaf(a2, __uint_as_float(v2.y & 0xffff0000u), acc[k].w);
        acc[k].x = fmaf(a3, __uint_as_float(v3.x << 16), acc[k].x);
        acc[k].y = fmaf(a3, __uint_as_float(v3.x & 0xffff0000u), acc[k].y);
        acc[k].z = fmaf(a3, __uint_as_float(v3.y << 16), acc[k].z);
        acc[k].w = fmaf(a3, __uint_as_float(v3.y & 0xffff0000u), acc[k].w);
      }
      for (; j < e; ++j) {
        int2 e0 = ebuf[j];
        float a0 = __int_as_float(e0.y);
        uint2 v0 = sb[(size_t)(e0.x & 0x1FFFF) * 32 + q];
        acc[k].x = fmaf(a0, __uint_as_float(v0.x << 16), acc[k].x);
        acc[k].y = fmaf(a0, __uint_as_float(v0.x & 0xffff0000u), acc[k].y);
        acc[k].z = fmaf(a0, __uint_as_float(v0.y << 16), acc[k].z);
        acc[k].w = fmaf(a0, __uint_as_float(v0.y & 0xffff0000u), acc[k].w);
      }
    }
    __syncthreads();   // ebuf/cnt reused next window
  }

  // epilogue: out_row = relu(acc + y_row + bias), coalesced float4
  const float4 bv = *(const float4*)&bias[q * 4];
#pragma unroll
  for (int k = 0; k < 16; ++k) {
    int g = b * 128 + gi * 16 + k;
    if (g < nNodes) {
      float4 yv = *(const float4*)&y[(size_t)g * D + q * 4];
      float4 res;
      res.x = fmaxf(acc[k].x + yv.x + bv.x, 0.f);
      res.y = fmaxf(acc[k].y + yv.y + bv.y, 0.f);
      res.z = fmaxf(acc[k].z + yv.z + bv.z, 0.f);
      res.w = fmaxf(acc[k].w + yv.w + bv.w, 0.f);
      *(float4*)&out[(size_t)g * D + q * 4] = res;
    }
  }
}

// ======================= tier-2/3 fallbacks (proven) =======================
__global__ __launch_bounds__(256) void zero_counts_kernel(int* __restrict__ c, int n) {
  int i = blockIdx.x * 256 + threadIdx.x;
  if (i < n) c[i] = 0;
}

__global__ __launch_bounds__(256) void hist_kernel(
    const int* __restrict__ dst, int* __restrict__ counts, int nE) {
  int e = blockIdx.x * 256 + threadIdx.x;
  if (e < nE) atomicAdd(&counts[dst[e]], 1);
}

__global__ __launch_bounds__(256) void scan_partial_kernel(
    const int* __restrict__ counts, int* __restrict__ chunk_sum, int n) {
  __shared__ int sdata[256];
  int b = blockIdx.x, t = threadIdx.x;
  int base = b * CHUNK + t * 4;
  int s = 0;
#pragma unroll
  for (int k = 0; k < 4; ++k) {
    int i = base + k;
    if (i < n) s += counts[i];
  }
  sdata[t] = s;
  __syncthreads();
  for (int off = 128; off > 0; off >>= 1) {
    if (t < off) sdata[t] += sdata[t + off];
    __syncthreads();
  }
  if (t == 0) chunk_sum[b] = sdata[0];
}

__global__ void scan_chunks_kernel(const int* __restrict__ chunk_sum,
                                   int* __restrict__ chunk_off,
                                   int* __restrict__ row_start, int nchunks, int n) {
  if (threadIdx.x == 0 && blockIdx.x == 0) {
    int run = 0;
    for (int i = 0; i < nchunks; ++i) {
      chunk_off[i] = run;
      run += chunk_sum[i];
    }
    row_start[n] = run;
  }
}

__global__ __launch_bounds__(256) void scan_final_kernel(
    const int* __restrict__ counts, const int* __restrict__ chunk_off,
    int* __restrict__ row_start, int* __restrict__ cursor, int n) {
  __shared__ int sdata[256];
  int b = blockIdx.x, t = threadIdx.x;
  int base = b * CHUNK + t * 4;
  int c[4] = {0, 0, 0, 0};
#pragma unroll
  for (int k = 0; k < 4; ++k) {
    int i = base + k;
    if (i < n) c[k] = counts[i];
  }
  int tsum = c[0] + c[1] + c[2] + c[3];
  sdata[t] = tsum;
  __syncthreads();
  for (int off = 1; off < 256; off <<= 1) {
    int v = (t >= off) ? sdata[t - off] : 0;
    __syncthreads();
    sdata[t] += v;
    __syncthreads();
  }
  int run = sdata[t] - tsum + chunk_off[b];
#pragma unroll
  for (int k = 0; k < 4; ++k) {
    int i = base + k;
    if (i < n) {
      row_start[i] = run;
      cursor[i] = run;
      run += c[k];
    }
  }
}

__global__ __launch_bounds__(256) void scatter_sort_kernel(
    const int* __restrict__ src, const int* __restrict__ dst,
    const float* __restrict__ adj, int* __restrict__ cursor,
    int2* __restrict__ edges, int nE) {
  int e = blockIdx.x * 256 + threadIdx.x;
  if (e >= nE) return;
  int d = dst[e];
  int2 ev;
  ev.x = src[e];
  ev.y = __float_as_int(adj[e]);
  int pos = atomicAdd(&cursor[d], 1);
  edges[pos] = ev;
}

__global__ __launch_bounds__(256) void gather_fp32_kernel(
    const float* __restrict__ x, const int* __restrict__ row_start,
    const int2* __restrict__ edges, float* __restrict__ out, int nNodes) {
  int g = (blockIdx.x * 256 + threadIdx.x) >> 5;
  int q = threadIdx.x & 31;
  if (g >= nNodes) return;
  int beg = row_start[g], end = row_start[g + 1];
  const float4* x4 = (const float4*)x;
  float4 acc = make_float4(0.f, 0.f, 0.f, 0.f);
  for (int j = beg; j < end; ++j) {
    int2 e0 = edges[j];
    float a0 = __int_as_float(e0.y);
    float4 v0 = x4[(size_t)e0.x * 32 + q];
    acc.x = fmaf(a0, v0.x, acc.x);
    acc.y = fmaf(a0, v0.y, acc.y);
    acc.z = fmaf(a0, v0.z, acc.z);
    acc.w = fmaf(a0, v0.w, acc.w);
  }
  ((float4*)out)[(size_t)g * 32 + q] = acc;
}

__global__ __launch_bounds__(256) void zero_kernel(float4* __restrict__ out, int n4) {
  int i = blockIdx.x * 256 + threadIdx.x;
  if (i < n4) out[i] = make_float4(0.f, 0.f, 0.f, 0.f);
}

__global__ __launch_bounds__(256) void scatter_atomic_kernel(
    const float* __restrict__ x, const int* __restrict__ src,
    const int* __restrict__ dst, const float* __restrict__ adj,
    float* __restrict__ out, int nE) {
  int tid = blockIdx.x * 256 + threadIdx.x;
  int e = tid >> 5;
  int q = tid & 31;
  if (e >= nE) return;
  int s = src[e];
  int d = dst[e];
  float a = adj[e];
  float4 v = ((const float4*)x)[(size_t)s * 32 + q];
  float* o = out + (size_t)d * D + q * 4;
  atomicAdd(o + 0, v.x * a);
  atomicAdd(o + 1, v.y * a);
  atomicAdd(o + 2, v.z * a);
  atomicAdd(o + 3, v.w * a);
}

// tier-2/3 epilogue GEMM (fp32 in-place)
__global__ __launch_bounds__(256) void gemm_fused_kernel(
    float* __restrict__ out, const float* __restrict__ w,
    const float* __restrict__ y, const float* __restrict__ bias, int nrows) {
  __shared__ float sW[D * D];
  __shared__ float sA[32 * D];
  const int tid = threadIdx.x;
  const int row0 = blockIdx.x * 32;

  const float4* w4 = (const float4*)w;
  float4* sW4 = (float4*)sW;
  for (int i = tid; i < D * D / 4; i += 256) sW4[i] = w4[i];

  const int nrow_blk = min(32, nrows - row0);
  const float4* out4_base = (const float4*)(out + (size_t)row0 * D);
  float4* sA4 = (float4*)sA;
  for (int i = tid; i < nrow_blk * 32; i += 256) sA4[i] = out4_base[i];
  __syncthreads();

  const int cg = tid & 31;
  const int rs = tid >> 5;

  float4 acc[4];
#pragma unroll
  for (int r = 0; r < 4; ++r) acc[r] = make_float4(0.f, 0.f, 0.f, 0.f);

#pragma unroll 4
  for (int k4 = 0; k4 < 32; ++k4) {
    float4 wv0 = sW4[(k4 * 4 + 0) * 32 + cg];
    float4 wv1 = sW4[(k4 * 4 + 1) * 32 + cg];
    float4 wv2 = sW4[(k4 * 4 + 2) * 32 + cg];
    float4 wv3 = sW4[(k4 * 4 + 3) * 32 + cg];
#pragma unroll
    for (int r = 0; r < 4; ++r) {
      float4 xv = sA4[(rs + r * 8) * 32 + k4];
      acc[r].x = fmaf(xv.x, wv0.x, acc[r].x);
      acc[r].y = fmaf(xv.x, wv0.y, acc[r].y);
      acc[r].z = fmaf(xv.x, wv0.z, acc[r].z);
      acc[r].w = fmaf(xv.x, wv0.w, acc[r].w);
      acc[r].x = fmaf(xv.y, wv1.x, acc[r].x);
      acc[r].y = fmaf(xv.y, wv1.y, acc[r].y);
      acc[r].z = fmaf(xv.y, wv1.z, acc[r].z);
      acc[r].w = fmaf(xv.y, wv1.w, acc[r].w);
      acc[r].x = fmaf(xv.z, wv2.x, acc[r].x);
      acc[r].y = fmaf(xv.z, wv2.y, acc[r].y);
      acc[r].z = fmaf(xv.z, wv2.z, acc[r].z);
      acc[r].w = fmaf(xv.z, wv2.w, acc[r].w);
      acc[r].x = fmaf(xv.w, wv3.x, acc[r].x);
      acc[r].y = fmaf(xv.w, wv3.y, acc[r].y);
      acc[r].z = fmaf(xv.w, wv3.z, acc[r].z);
      acc[r].w = fmaf(xv.w, wv3.w, acc[r].w);
    }
  }

  const float4* y4 = (const float4*)y;
  const float4* b4 = (const float4*)bias;
  float4* o4 = (float4*)out;
  float4 bv = b4[cg];
#pragma unroll
  for (int r = 0; r < 4; ++r) {
    int row = row0 + rs + r * 8;
    if (row < nrows) {
      float4 yv = y4[(size_t)row * 32 + cg];
      float4 res;
      res.x = fmaxf(acc[r].x + yv.x + bv.x, 0.f);
      res.y = fmaxf(acc[r].y + yv.y + bv.y, 0.f);
      res.z = fmaxf(acc[r].z + yv.z + bv.z, 0.f);
      res.w = fmaxf(acc[r].w + yv.w + bv.w, 0.f);
      o4[(size_t)row * 32 + cg] = res;
    }
  }
}

extern "C" void kernel_launch(void* const* d_in, const int* in_sizes, int n_in,
                              void* d_out, int out_size, void* d_ws, size_t ws_size,
                              hipStream_t stream) {
  const float* x    = (const float*)d_in[0];
  const float* y    = (const float*)d_in[1];
  const int*   esrc = (const int*)d_in[2];
  const int*   edst = (const int*)d_in[3];
  const float* adj  = (const float*)d_in[4];
  const float* w    = (const float*)d_in[5];
  const float* bias = (const float*)d_in[6];
  float* out = (float*)d_out;

  const int nNodes = in_sizes[0] / D;
  const int nE = in_sizes[2];
  const int n4 = nNodes * (D / 4);
  const int nB = (nNodes + 127) >> 7;
  const int nC = (nE + CE - 1) / CE;

  // tier-1 ws: [ofs | wt | tmp | xb]  (xb becomes support table in-place)
  const size_t ofs_bytes = (((size_t)nC * (nB + 1) * 2) + 15) & ~(size_t)15;
  const size_t wt_bytes  = (size_t)D * WTP * 2;
  const size_t tmp_bytes = (size_t)nC * CE * 8;
  const size_t xb_bytes  = (size_t)nNodes * D * 2;
  const size_t need1 = ofs_bytes + wt_bytes + tmp_bytes + xb_bytes;

  const int nchunks = (nNodes + CHUNK - 1) / CHUNK;
  const size_t e2_bytes  = (size_t)nE * 8;
  const size_t int_bytes = (size_t)(3 * nNodes + 1 + 2 * nchunks) * 4;
  const size_t need2 = e2_bytes + int_bytes;

  if (ws_size >= need1 && nNodes <= NB_MAX * 128 && nC <= MAXC) {
    char* p = (char*)d_ws;
    unsigned short* ofs = (unsigned short*)p;   p += ofs_bytes;
    unsigned short* wt = (unsigned short*)p;    p += wt_bytes;
    int2* tmp = (int2*)p;                       p += tmp_bytes;
    unsigned short* xb = (unsigned short*)p;    // xb -> support (in-place)

    const int nxblk = (n4 + 1023) / 1024;
    const int wtblk = (D * D + 1023) / 1024;
    sort_convert_kernel<<<nC + nxblk + wtblk, 1024, 0, stream>>>(
        esrc, edst, adj, tmp, ofs, nE, nB, nC,
        (const float4*)x, (ushort4*)xb, n4, nxblk, w, wt);
    gemm_support_kernel<<<(nNodes + 127) / 128, 256, 0, stream>>>(
        xb, wt, nNodes);
    gather_final_kernel<<<nB, 256, 0, stream>>>(
        tmp, ofs, (const uint2*)xb, y, bias, out, nC, nB, nNodes);
  } else if (ws_size >= need2) {
    char* base = (char*)d_ws;
    int2* edges = (int2*)base;
    int* counts = (int*)(base + e2_bytes);
    int* row_start = counts + nNodes;
    int* cursor = row_start + nNodes + 1;
    int* chunk_sum = cursor + nNodes;
    int* chunk_off = chunk_sum + nchunks;

    zero_counts_kernel<<<(nNodes + 255) / 256, 256, 0, stream>>>(counts, nNodes);
    hist_kernel<<<(nE + 255) / 256, 256, 0, stream>>>(edst, counts, nE);
    scan_partial_kernel<<<nchunks, 256, 0, stream>>>(counts, chunk_sum, nNodes);
    scan_chunks_kernel<<<1, 64, 0, stream>>>(chunk_sum, chunk_off, row_start,
                                             nchunks, nNodes);
    scan_final_kernel<<<nchunks, 256, 0, stream>>>(counts, chunk_off, row_start,
                                                   cursor, nNodes);
    scatter_sort_kernel<<<(nE + 255) / 256, 256, 0, stream>>>(
        esrc, edst, adj, cursor, edges, nE);
    gather_fp32_kernel<<<(nNodes * 32 + 255) / 256, 256, 0, stream>>>(
        x, row_start, edges, out, nNodes);
    gemm_fused_kernel<<<(nNodes + 31) / 32, 256, 0, stream>>>(out, w, y, bias,
                                                              nNodes);
  } else {
    zero_kernel<<<(n4 + 255) / 256, 256, 0, stream>>>((float4*)out, n4);
    scatter_atomic_kernel<<<((size_t)nE * 32 + 255) / 256, 256, 0, stream>>>(
        x, esrc, edst, adj, out, nE);
    gemm_fused_kernel<<<(nNodes + 31) / 32, 256, 0, stream>>>(out, w, y, bias,
                                                              nNodes);
  }
}